// Round 6
// baseline (613.277 us; speedup 1.0000x reference)
//
#include <hip/hip_runtime.h>
#include <stdint.h>

#define TOPK 100
#define GCAP 2048
#define FIL_GRID 1024

typedef __attribute__((ext_vector_type(8))) short bf16x8;
typedef __attribute__((ext_vector_type(4))) float f32x4;

__device__ __forceinline__ unsigned int fsort(float f) {
  unsigned int u = __float_as_uint(f);
  return (u & 0x80000000u) ? ~u : (u | 0x80000000u);
}
__device__ __forceinline__ float funsort(unsigned int k) {
  unsigned int u = (k & 0x80000000u) ? (k ^ 0x80000000u) : ~k;
  return __uint_as_float(u);
}
__device__ __forceinline__ unsigned short f2bf(float f) {
  unsigned int u = __float_as_uint(f);
  unsigned int r = (u + 0x7fffu + ((u >> 16) & 1u)) >> 16;  // RNE
  return (unsigned short)r;
}

// ------- Kernel 1: per-user sample threshold + cnt zero + user bf16 panel ----
__global__ void k_sample(const float* __restrict__ user,
                         const float* __restrict__ corpus,
                         float* __restrict__ thr,
                         unsigned int* __restrict__ cnt,
                         unsigned short* __restrict__ ubf,
                         int M, int rank) {
  __shared__ float s_scores[16384];
  __shared__ float s_user[64];
  __shared__ unsigned int s_hist[256];
  __shared__ float s_wred[8];
  __shared__ float s_bmax, s_bmin;

  const int u = blockIdx.x;
  const int t = threadIdx.x;
  if (t == 0) cnt[u] = 0u;
  if (t < 64) {
    float v = user[u * 64 + t];
    s_user[t] = v;
    ubf[u * 64 + t] = f2bf(v);
  }
  __syncthreads();

  float uv[64];
#pragma unroll
  for (int i = 0; i < 64; ++i) uv[i] = s_user[i];

  float lmax = -3.0e38f, lmin = 3.0e38f;
  for (int r = t; r < M; r += 256) {
    const float4* row = (const float4*)(corpus + (size_t)r * 64);
    float acc = 0.f;
#pragma unroll
    for (int i = 0; i < 16; ++i) {
      float4 c = row[i];
      acc = fmaf(uv[4*i+0], c.x, acc);
      acc = fmaf(uv[4*i+1], c.y, acc);
      acc = fmaf(uv[4*i+2], c.z, acc);
      acc = fmaf(uv[4*i+3], c.w, acc);
    }
    s_scores[r] = acc;
    lmax = fmaxf(lmax, acc);
    lmin = fminf(lmin, acc);
  }
#pragma unroll
  for (int o = 32; o > 0; o >>= 1) {
    lmax = fmaxf(lmax, __shfl_down(lmax, o));
    lmin = fminf(lmin, __shfl_down(lmin, o));
  }
  if ((t & 63) == 0) { s_wred[t >> 6] = lmax; s_wred[4 + (t >> 6)] = lmin; }
  s_hist[t] = 0u;
  __syncthreads();
  if (t == 0) {
    float bm = s_wred[0], bn = s_wred[4];
    for (int w = 1; w < 4; ++w) { bm = fmaxf(bm, s_wred[w]); bn = fminf(bn, s_wred[4 + w]); }
    s_bmax = bm; s_bmin = bn;
  }
  __syncthreads();
  const float bmax = s_bmax, bmin = s_bmin;
  const float width = (bmax - bmin) / 256.0f;
  const float inv = (width > 0.f) ? 1.0f / width : 0.f;
  for (int r = t; r < M; r += 256) {
    int b = (int)((s_scores[r] - bmin) * inv);
    b = min(max(b, 0), 255);
    atomicAdd(&s_hist[b], 1u);
  }
  __syncthreads();
  if (t == 0) {
    unsigned int cum = 0;
    int b = 255;
    for (; b >= 0; --b) { cum += s_hist[b]; if (cum >= (unsigned int)rank) break; }
    if (b < 0) b = 0;
    thr[u] = bmin + width * (float)b;
  }
}

// ------- Kernel 2: MFMA bf16 filter, software-pipelined ------------------
// Persistent grid (1024 blocks x 61 tiles). Per iteration: prefetch next
// tile's 4 float4 loads BEFORE computing current tile; per-ut ballot skips
// the branchy atomic section when no lane has a survivor (~73% of the time).
__global__ __launch_bounds__(256) void k_filter(
    const float* __restrict__ corpus,
    const unsigned short* __restrict__ ubf,
    const float* __restrict__ thr,
    unsigned int* __restrict__ cnt,
    unsigned long long* __restrict__ cand,
    int N, int CAP, int ntiles, float margin) {
  const int t = threadIdx.x;
  const int lane = t & 63;
  const int wave = t >> 6;
  const int l15 = lane & 15;
  const int l4  = lane >> 4;
  const int ubase = wave * 64;

  bf16x8 bf[4][2];
#pragma unroll
  for (int ut = 0; ut < 4; ++ut) {
    const int uu = ubase + ut * 16 + l15;
#pragma unroll
    for (int kh = 0; kh < 2; ++kh)
      bf[ut][kh] = *(const bf16x8*)(ubf + uu * 64 + kh * 32 + l4 * 8);
  }
  float thv[4];
#pragma unroll
  for (int ut = 0; ut < 4; ++ut) thv[ut] = thr[ubase + ut * 16 + l15] - margin;

  int tile = blockIdx.x;
  if (tile >= ntiles) return;

  // prologue load
  long long rowc = (long long)min(tile * 16 + l15, N - 1);
  const float4* rp = (const float4*)(corpus + rowc * 64);
  float4 c00 = rp[l4 * 2 + 0];
  float4 c01 = rp[l4 * 2 + 1];
  float4 c10 = rp[8 + l4 * 2 + 0];
  float4 c11 = rp[8 + l4 * 2 + 1];

  for (;;) {
    const int next = tile + gridDim.x;
    const bool have_next = (next < ntiles);
    float4 n00, n01, n10, n11;
    if (have_next) {                      // prefetch next tile (hidden under compute)
      long long rowc2 = (long long)min(next * 16 + l15, N - 1);
      const float4* rp2 = (const float4*)(corpus + rowc2 * 64);
      n00 = rp2[l4 * 2 + 0];
      n01 = rp2[l4 * 2 + 1];
      n10 = rp2[8 + l4 * 2 + 0];
      n11 = rp2[8 + l4 * 2 + 1];
    }

    // convert current tile to bf16 A-frags
    bf16x8 af0, af1;
    af0[0] = (short)f2bf(c00.x); af0[1] = (short)f2bf(c00.y);
    af0[2] = (short)f2bf(c00.z); af0[3] = (short)f2bf(c00.w);
    af0[4] = (short)f2bf(c01.x); af0[5] = (short)f2bf(c01.y);
    af0[6] = (short)f2bf(c01.z); af0[7] = (short)f2bf(c01.w);
    af1[0] = (short)f2bf(c10.x); af1[1] = (short)f2bf(c10.y);
    af1[2] = (short)f2bf(c10.z); af1[3] = (short)f2bf(c10.w);
    af1[4] = (short)f2bf(c11.x); af1[5] = (short)f2bf(c11.y);
    af1[6] = (short)f2bf(c11.z); af1[7] = (short)f2bf(c11.w);

    f32x4 acc[4];
#pragma unroll
    for (int ut = 0; ut < 4; ++ut) acc[ut] = (f32x4){0.f, 0.f, 0.f, 0.f};
#pragma unroll
    for (int ut = 0; ut < 4; ++ut) {
      acc[ut] = __builtin_amdgcn_mfma_f32_16x16x32_bf16(af0, bf[ut][0], acc[ut], 0, 0, 0);
      acc[ut] = __builtin_amdgcn_mfma_f32_16x16x32_bf16(af1, bf[ut][1], acc[ut], 0, 0, 0);
    }

    const int rb = tile << 4;
#pragma unroll
    for (int ut = 0; ut < 4; ++ut) {
      bool hit = (acc[ut][0] >= thv[ut]) | (acc[ut][1] >= thv[ut]) |
                 (acc[ut][2] >= thv[ut]) | (acc[ut][3] >= thv[ut]);
      if (__ballot(hit)) {                // rare slow path (~27% per ut)
        const int uu = ubase + ut * 16 + l15;
#pragma unroll
        for (int r = 0; r < 4; ++r) {
          const int row = rb + l4 * 4 + r;
          const float s = acc[ut][r];
          if (s >= thv[ut] && row < N) {
            unsigned int pos = atomicAdd(&cnt[uu], 1u);
            if (pos < (unsigned int)CAP)
              cand[(size_t)uu * (size_t)CAP + pos] = (unsigned long long)(unsigned int)row;
          }
        }
      }
    }

    if (!have_next) break;
    tile = next;
    c00 = n00; c01 = n01; c10 = n10; c11 = n11;
  }
}

// ------- Kernel 3: exact fp32 rescore of survivors (in-place keys) --------
// grid = B*4: block handles quarter q of user u's list.
__global__ void k_rescore(const float* __restrict__ user,
                          const float* __restrict__ corpus,
                          const unsigned int* __restrict__ cnt,
                          unsigned long long* __restrict__ cand,
                          int CAP) {
  __shared__ float su[64];
  const int u = blockIdx.x >> 2;
  const int q = blockIdx.x & 3;
  const int t = threadIdx.x;
  if (t < 64) su[t] = user[u * 64 + t];
  __syncthreads();
  float uv[64];
#pragma unroll
  for (int i = 0; i < 64; ++i) uv[i] = su[i];
  const int n = min((int)cnt[u], CAP);
  for (int i = q * 256 + t; i < n; i += 1024) {
    const unsigned int row = (unsigned int)cand[(size_t)u * (size_t)CAP + i];
    const float4* rp = (const float4*)(corpus + (size_t)row * 64);
    float acc = 0.f;
#pragma unroll
    for (int k = 0; k < 16; ++k) {
      float4 c = rp[k];
      acc = fmaf(uv[4*k+0], c.x, acc);
      acc = fmaf(uv[4*k+1], c.y, acc);
      acc = fmaf(uv[4*k+2], c.z, acc);
      acc = fmaf(uv[4*k+3], c.w, acc);
    }
    cand[(size_t)u * (size_t)CAP + i] = ((unsigned long long)fsort(acc) << 32)
                                      | (unsigned long long)(~row);
  }
}

// ------- Kernel 4: exact top-100 per user ---------------------------------
__global__ void k_select(const unsigned long long* __restrict__ cand,
                         const unsigned int* __restrict__ cnt,
                         float* __restrict__ out,
                         int B, int CAP) {
  __shared__ unsigned long long keys[GCAP];
  __shared__ unsigned int hist[1024];
  __shared__ unsigned int s_kmax, s_kmin, s_gcnt;
  __shared__ int s_bstar;

  const int u = blockIdx.x;
  const int t = threadIdx.x;
  const int n = min((int)cnt[u], CAP);
  const unsigned long long* cu = cand + (size_t)u * (size_t)CAP;

  if (t == 0) { s_kmax = 0u; s_kmin = 0xFFFFFFFFu; s_gcnt = 0u; }
  for (int i = t; i < 1024; i += 256) hist[i] = 0u;
  __syncthreads();

  unsigned int lmax = 0u, lmin = 0xFFFFFFFFu;
  for (int i = t; i < n; i += 256) {
    unsigned int k = (unsigned int)(cu[i] >> 32);
    lmax = max(lmax, k); lmin = min(lmin, k);
  }
#pragma unroll
  for (int o = 32; o > 0; o >>= 1) {
    lmax = max(lmax, __shfl_down(lmax, o));
    lmin = min(lmin, __shfl_down(lmin, o));
  }
  if ((t & 63) == 0) { atomicMax(&s_kmax, lmax); atomicMin(&s_kmin, lmin); }
  __syncthreads();
  const unsigned int kmax = s_kmax, kmin = s_kmin;
  const unsigned long long range = (unsigned long long)(kmax - kmin) + 1ull;

  for (int i = t; i < n; i += 256) {
    unsigned int k = (unsigned int)(cu[i] >> 32);
    unsigned int b = (unsigned int)((((unsigned long long)(k - kmin)) << 10) / range);
    atomicAdd(&hist[min(b, 1023u)], 1u);
  }
  __syncthreads();
  if (t == 0) {
    unsigned int cum = 0;
    int b = 1023;
    for (; b >= 0; --b) { cum += hist[b]; if (cum >= TOPK) break; }
    s_bstar = (b < 0) ? 0 : b;
  }
  __syncthreads();
  const unsigned int bstar = (unsigned int)s_bstar;

  for (int i = t; i < n; i += 256) {
    unsigned long long key = cu[i];
    unsigned int k = (unsigned int)(key >> 32);
    unsigned int b = min((unsigned int)((((unsigned long long)(k - kmin)) << 10) / range), 1023u);
    if (b >= bstar) {
      unsigned int pos = atomicAdd(&s_gcnt, 1u);
      if (pos < GCAP) keys[pos] = key;
    }
  }
  __syncthreads();
  const int g = min((int)s_gcnt, GCAP);
  int S = 128;
  while (S < g) S <<= 1;
  for (int i = g + t; i < S; i += 256) keys[i] = 0ull;
  __syncthreads();

  for (int k = 2; k <= S; k <<= 1) {
    for (int j = k >> 1; j > 0; j >>= 1) {
      for (int i = t; i < S; i += 256) {
        int ixj = i ^ j;
        if (ixj > i) {
          unsigned long long a = keys[i], b2 = keys[ixj];
          bool descSeg = ((i & k) == 0);
          bool sw = descSeg ? (a < b2) : (a > b2);
          if (sw) { keys[i] = b2; keys[ixj] = a; }
        }
      }
      __syncthreads();
    }
  }

  if (t < TOPK) {
    unsigned long long key = keys[t];
    unsigned int kk = (unsigned int)(key >> 32);
    unsigned int idx = ~(unsigned int)(key & 0xFFFFFFFFull);
    out[u * TOPK + t] = funsort(kk);
    out[(size_t)B * TOPK + u * TOPK + t] = (float)idx;
  }
}

extern "C" void kernel_launch(void* const* d_in, const int* in_sizes, int n_in,
                              void* d_out, int out_size, void* d_ws, size_t ws_size,
                              hipStream_t stream) {
  const float* user = (const float*)d_in[0];
  const float* corpus = (const float*)d_in[1];
  float* out = (float*)d_out;
  const int B = in_sizes[0] / 64;           // 256
  const int N = in_sizes[1] / 64;           // 1,000,000

  // ws: cnt[B] u32 @0 | thr[B] f32 @1024 | ubf[B*64] u16 @2048 | cand u64 @34816
  unsigned int* cnt = (unsigned int*)d_ws;
  float* thr = (float*)((char*)d_ws + 1024);
  unsigned short* ubf = (unsigned short*)((char*)d_ws + 2048);
  unsigned long long* cand = (unsigned long long*)((char*)d_ws + 34816);

  long long avail = ((long long)ws_size - 34816) / ((long long)B * 8);
  int CAP = 4096;                    // survivors ~1230 +/- 280
  if (avail < CAP) CAP = (int)avail;
  if (CAP < 256) CAP = 256;
  const int M = (N < 16384) ? N : 16384;
  const int RANK = 16;
  const float MARGIN = 0.25f;
  const int ntiles = (N + 15) >> 4;

  k_sample<<<B, 256, 0, stream>>>(user, corpus, thr, cnt, ubf, M, RANK);
  k_filter<<<FIL_GRID, 256, 0, stream>>>(corpus, ubf, thr, cnt, cand, N, CAP, ntiles, MARGIN);
  k_rescore<<<B * 4, 256, 0, stream>>>(user, corpus, cnt, cand, CAP);
  k_select<<<B, 256, 0, stream>>>(cand, cnt, out, B, CAP);
}

// Round 7
// 390.954 us; speedup vs baseline: 1.5687x; 1.5687x over previous
//
#include <hip/hip_runtime.h>
#include <stdint.h>

#define TOPK 100
#define GCAP 2048
#define FIL_BLOCKS 1024
#define SLIST_CAP 2048

typedef __attribute__((ext_vector_type(8))) short bf16x8;
typedef __attribute__((ext_vector_type(4))) float f32x4;

__device__ __forceinline__ unsigned int fsort(float f) {
  unsigned int u = __float_as_uint(f);
  return (u & 0x80000000u) ? ~u : (u | 0x80000000u);
}
__device__ __forceinline__ float funsort(unsigned int k) {
  unsigned int u = (k & 0x80000000u) ? (k ^ 0x80000000u) : ~k;
  return __uint_as_float(u);
}
__device__ __forceinline__ unsigned short f2bf(float f) {
  unsigned int u = __float_as_uint(f);
  unsigned int r = (u + 0x7fffu + ((u >> 16) & 1u)) >> 16;  // RNE
  return (unsigned short)r;
}

// cnt is padded: user u's counter lives at cnt[u*16] (64 B apart).

// ------- Kernel 1: per-user sample threshold + cnt zero + user bf16 panel ----
__global__ void k_sample(const float* __restrict__ user,
                         const float* __restrict__ corpus,
                         float* __restrict__ thr,
                         unsigned int* __restrict__ cnt,
                         unsigned short* __restrict__ ubf,
                         int M, int rank) {
  __shared__ float s_scores[16384];
  __shared__ float s_user[64];
  __shared__ unsigned int s_hist[256];
  __shared__ float s_wred[8];
  __shared__ float s_bmax, s_bmin;

  const int u = blockIdx.x;
  const int t = threadIdx.x;
  if (t == 0) cnt[u * 16] = 0u;
  if (t < 64) {
    float v = user[u * 64 + t];
    s_user[t] = v;
    ubf[u * 64 + t] = f2bf(v);
  }
  __syncthreads();

  float uv[64];
#pragma unroll
  for (int i = 0; i < 64; ++i) uv[i] = s_user[i];

  float lmax = -3.0e38f, lmin = 3.0e38f;
  for (int r = t; r < M; r += 256) {
    const float4* row = (const float4*)(corpus + (size_t)r * 64);
    float acc = 0.f;
#pragma unroll
    for (int i = 0; i < 16; ++i) {
      float4 c = row[i];
      acc = fmaf(uv[4*i+0], c.x, acc);
      acc = fmaf(uv[4*i+1], c.y, acc);
      acc = fmaf(uv[4*i+2], c.z, acc);
      acc = fmaf(uv[4*i+3], c.w, acc);
    }
    s_scores[r] = acc;
    lmax = fmaxf(lmax, acc);
    lmin = fminf(lmin, acc);
  }
#pragma unroll
  for (int o = 32; o > 0; o >>= 1) {
    lmax = fmaxf(lmax, __shfl_down(lmax, o));
    lmin = fminf(lmin, __shfl_down(lmin, o));
  }
  if ((t & 63) == 0) { s_wred[t >> 6] = lmax; s_wred[4 + (t >> 6)] = lmin; }
  s_hist[t] = 0u;
  __syncthreads();
  if (t == 0) {
    float bm = s_wred[0], bn = s_wred[4];
    for (int w = 1; w < 4; ++w) { bm = fmaxf(bm, s_wred[w]); bn = fminf(bn, s_wred[4 + w]); }
    s_bmax = bm; s_bmin = bn;
  }
  __syncthreads();
  const float bmax = s_bmax, bmin = s_bmin;
  const float width = (bmax - bmin) / 256.0f;
  const float inv = (width > 0.f) ? 1.0f / width : 0.f;
  for (int r = t; r < M; r += 256) {
    int b = (int)((s_scores[r] - bmin) * inv);
    b = min(max(b, 0), 255);
    atomicAdd(&s_hist[b], 1u);
  }
  __syncthreads();
  if (t == 0) {
    unsigned int cum = 0;
    int b = 255;
    for (; b >= 0; --b) { cum += s_hist[b]; if (cum >= (unsigned int)rank) break; }
    if (b < 0) b = 0;
    thr[u] = bmin + width * (float)b;
  }
}

// ------- Kernel 2: MFMA bf16 filter — one tile per WAVE, LDS-staged survivors
// Wave = 1 corpus tile stream vs ALL 256 users (16 ut groups, frags in VGPR).
// Hot loop: 4 prefetched dwordx4, 32 f2bf, 32 MFMA, 64 compares, rare LDS
// appends. NO global atomics until block-end flush (1 per block-user).
__global__ __launch_bounds__(256, 2) void k_filter(
    const float* __restrict__ corpus,
    const unsigned short* __restrict__ ubf,
    const float* __restrict__ thr,
    unsigned int* __restrict__ cnt,
    unsigned long long* __restrict__ cand,
    int N, int CAP, int ntiles, float margin) {
  __shared__ unsigned int slist[SLIST_CAP];
  __shared__ unsigned int scnt;

  const int t = threadIdx.x;
  const int lane = t & 63;
  const int wave = t >> 6;
  const int l15 = lane & 15;
  const int l4  = lane >> 4;

  if (t == 0) scnt = 0u;
  __syncthreads();

  // B-frags for ALL users: bf[ut][kh], user = ut*16 + l15
  bf16x8 bf[16][2];
  float thv[16];
#pragma unroll
  for (int ut = 0; ut < 16; ++ut) {
    const int uu = ut * 16 + l15;
#pragma unroll
    for (int kh = 0; kh < 2; ++kh)
      bf[ut][kh] = *(const bf16x8*)(ubf + uu * 64 + kh * 32 + l4 * 8);
    thv[ut] = thr[uu] - margin;
  }

  const int stride = FIL_BLOCKS * 4;
  int tile = blockIdx.x * 4 + wave;

  if (tile < ntiles) {
    long long rowc = (long long)min(tile * 16 + l15, N - 1);
    const float4* rp = (const float4*)(corpus + rowc * 64);
    float4 c00 = rp[l4 * 2 + 0];
    float4 c01 = rp[l4 * 2 + 1];
    float4 c10 = rp[8 + l4 * 2 + 0];
    float4 c11 = rp[8 + l4 * 2 + 1];

    for (;;) {
      const int next = tile + stride;
      const bool have_next = (next < ntiles);
      float4 n00, n01, n10, n11;
      if (have_next) {
        long long rowc2 = (long long)min(next * 16 + l15, N - 1);
        const float4* rp2 = (const float4*)(corpus + rowc2 * 64);
        n00 = rp2[l4 * 2 + 0];
        n01 = rp2[l4 * 2 + 1];
        n10 = rp2[8 + l4 * 2 + 0];
        n11 = rp2[8 + l4 * 2 + 1];
      }

      bf16x8 af0, af1;
      af0[0] = (short)f2bf(c00.x); af0[1] = (short)f2bf(c00.y);
      af0[2] = (short)f2bf(c00.z); af0[3] = (short)f2bf(c00.w);
      af0[4] = (short)f2bf(c01.x); af0[5] = (short)f2bf(c01.y);
      af0[6] = (short)f2bf(c01.z); af0[7] = (short)f2bf(c01.w);
      af1[0] = (short)f2bf(c10.x); af1[1] = (short)f2bf(c10.y);
      af1[2] = (short)f2bf(c10.z); af1[3] = (short)f2bf(c10.w);
      af1[4] = (short)f2bf(c11.x); af1[5] = (short)f2bf(c11.y);
      af1[6] = (short)f2bf(c11.z); af1[7] = (short)f2bf(c11.w);

      const int rb = tile << 4;
#pragma unroll
      for (int ut = 0; ut < 16; ++ut) {
        f32x4 acc = (f32x4){0.f, 0.f, 0.f, 0.f};
        acc = __builtin_amdgcn_mfma_f32_16x16x32_bf16(af0, bf[ut][0], acc, 0, 0, 0);
        acc = __builtin_amdgcn_mfma_f32_16x16x32_bf16(af1, bf[ut][1], acc, 0, 0, 0);
        bool hit = (acc[0] >= thv[ut]) | (acc[1] >= thv[ut]) |
                   (acc[2] >= thv[ut]) | (acc[3] >= thv[ut]);
        if (__ballot(hit)) {
          const unsigned int uu = (unsigned int)(ut * 16 + l15);
#pragma unroll
          for (int r = 0; r < 4; ++r) {
            const int row = rb + l4 * 4 + r;
            if (acc[r] >= thv[ut] && row < N) {
              unsigned int pos = atomicAdd(&scnt, 1u);
              if (pos < SLIST_CAP) {
                slist[pos] = (uu << 20) | (unsigned int)row;
              } else {  // degenerate-data fallback: direct global append
                unsigned int gp = atomicAdd(&cnt[uu * 16], 1u);
                if (gp < (unsigned int)CAP)
                  cand[(size_t)uu * (size_t)CAP + gp] = (unsigned long long)(unsigned int)row;
              }
            }
          }
        }
      }

      if (!have_next) break;
      tile = next;
      c00 = n00; c01 = n01; c10 = n10; c11 = n11;
    }
  }

  __syncthreads();
  // ---- flush: thread t owns user t; two broadcast scans of slist ----
  const int n = min((int)scnt, SLIST_CAP);
  const unsigned int me = (unsigned int)t;
  unsigned int c = 0;
  for (int i = 0; i < n; ++i)
    if ((slist[i] >> 20) == me) ++c;
  unsigned int base = 0;
  if (c) base = atomicAdd(&cnt[me * 16], c);
  if (c) {
    unsigned int k = 0;
    for (int i = 0; i < n; ++i) {
      unsigned int v = slist[i];
      if ((v >> 20) == me) {
        unsigned int p = base + k;
        if (p < (unsigned int)CAP)
          cand[(size_t)me * (size_t)CAP + p] = (unsigned long long)(v & 0xFFFFFu);
        ++k;
      }
    }
  }
}

// ------- Kernel 3: exact fp32 rescore of survivors (in-place keys) --------
__global__ void k_rescore(const float* __restrict__ user,
                          const float* __restrict__ corpus,
                          const unsigned int* __restrict__ cnt,
                          unsigned long long* __restrict__ cand,
                          int CAP) {
  __shared__ float su[64];
  const int u = blockIdx.x >> 2;
  const int q = blockIdx.x & 3;
  const int t = threadIdx.x;
  if (t < 64) su[t] = user[u * 64 + t];
  __syncthreads();
  float uv[64];
#pragma unroll
  for (int i = 0; i < 64; ++i) uv[i] = su[i];
  const int n = min((int)cnt[u * 16], CAP);
  for (int i = q * 256 + t; i < n; i += 1024) {
    const unsigned int row = (unsigned int)cand[(size_t)u * (size_t)CAP + i];
    const float4* rp = (const float4*)(corpus + (size_t)row * 64);
    float acc = 0.f;
#pragma unroll
    for (int k = 0; k < 16; ++k) {
      float4 c = rp[k];
      acc = fmaf(uv[4*k+0], c.x, acc);
      acc = fmaf(uv[4*k+1], c.y, acc);
      acc = fmaf(uv[4*k+2], c.z, acc);
      acc = fmaf(uv[4*k+3], c.w, acc);
    }
    cand[(size_t)u * (size_t)CAP + i] = ((unsigned long long)fsort(acc) << 32)
                                      | (unsigned long long)(~row);
  }
}

// ------- Kernel 4: exact top-100 per user ---------------------------------
__global__ void k_select(const unsigned long long* __restrict__ cand,
                         const unsigned int* __restrict__ cnt,
                         float* __restrict__ out,
                         int B, int CAP) {
  __shared__ unsigned long long keys[GCAP];
  __shared__ unsigned int hist[1024];
  __shared__ unsigned int s_kmax, s_kmin, s_gcnt;
  __shared__ int s_bstar;

  const int u = blockIdx.x;
  const int t = threadIdx.x;
  const int n = min((int)cnt[u * 16], CAP);
  const unsigned long long* cu = cand + (size_t)u * (size_t)CAP;

  if (t == 0) { s_kmax = 0u; s_kmin = 0xFFFFFFFFu; s_gcnt = 0u; }
  for (int i = t; i < 1024; i += 256) hist[i] = 0u;
  __syncthreads();

  unsigned int lmax = 0u, lmin = 0xFFFFFFFFu;
  for (int i = t; i < n; i += 256) {
    unsigned int k = (unsigned int)(cu[i] >> 32);
    lmax = max(lmax, k); lmin = min(lmin, k);
  }
#pragma unroll
  for (int o = 32; o > 0; o >>= 1) {
    lmax = max(lmax, __shfl_down(lmax, o));
    lmin = min(lmin, __shfl_down(lmin, o));
  }
  if ((t & 63) == 0) { atomicMax(&s_kmax, lmax); atomicMin(&s_kmin, lmin); }
  __syncthreads();
  const unsigned int kmax = s_kmax, kmin = s_kmin;
  const unsigned long long range = (unsigned long long)(kmax - kmin) + 1ull;

  for (int i = t; i < n; i += 256) {
    unsigned int k = (unsigned int)(cu[i] >> 32);
    unsigned int b = (unsigned int)((((unsigned long long)(k - kmin)) << 10) / range);
    atomicAdd(&hist[min(b, 1023u)], 1u);
  }
  __syncthreads();
  if (t == 0) {
    unsigned int cum = 0;
    int b = 1023;
    for (; b >= 0; --b) { cum += hist[b]; if (cum >= TOPK) break; }
    s_bstar = (b < 0) ? 0 : b;
  }
  __syncthreads();
  const unsigned int bstar = (unsigned int)s_bstar;

  for (int i = t; i < n; i += 256) {
    unsigned long long key = cu[i];
    unsigned int k = (unsigned int)(key >> 32);
    unsigned int b = min((unsigned int)((((unsigned long long)(k - kmin)) << 10) / range), 1023u);
    if (b >= bstar) {
      unsigned int pos = atomicAdd(&s_gcnt, 1u);
      if (pos < GCAP) keys[pos] = key;
    }
  }
  __syncthreads();
  const int g = min((int)s_gcnt, GCAP);
  int S = 128;
  while (S < g) S <<= 1;
  for (int i = g + t; i < S; i += 256) keys[i] = 0ull;
  __syncthreads();

  for (int k = 2; k <= S; k <<= 1) {
    for (int j = k >> 1; j > 0; j >>= 1) {
      for (int i = t; i < S; i += 256) {
        int ixj = i ^ j;
        if (ixj > i) {
          unsigned long long a = keys[i], b2 = keys[ixj];
          bool descSeg = ((i & k) == 0);
          bool sw = descSeg ? (a < b2) : (a > b2);
          if (sw) { keys[i] = b2; keys[ixj] = a; }
        }
      }
      __syncthreads();
    }
  }

  if (t < TOPK) {
    unsigned long long key = keys[t];
    unsigned int kk = (unsigned int)(key >> 32);
    unsigned int idx = ~(unsigned int)(key & 0xFFFFFFFFull);
    out[u * TOPK + t] = funsort(kk);
    out[(size_t)B * TOPK + u * TOPK + t] = (float)idx;
  }
}

extern "C" void kernel_launch(void* const* d_in, const int* in_sizes, int n_in,
                              void* d_out, int out_size, void* d_ws, size_t ws_size,
                              hipStream_t stream) {
  const float* user = (const float*)d_in[0];
  const float* corpus = (const float*)d_in[1];
  float* out = (float*)d_out;
  const int B = in_sizes[0] / 64;           // 256
  const int N = in_sizes[1] / 64;           // 1,000,000

  // ws: cnt_pad[B*16] u32 @0 (16 KB) | thr[B] f32 @16384 | ubf[B*64] u16 @17408
  //     | cand u64 @50176
  unsigned int* cnt = (unsigned int*)d_ws;
  float* thr = (float*)((char*)d_ws + 16384);
  unsigned short* ubf = (unsigned short*)((char*)d_ws + 17408);
  unsigned long long* cand = (unsigned long long*)((char*)d_ws + 50176);

  long long avail = ((long long)ws_size - 50176) / ((long long)B * 8);
  int CAP = 4096;                    // survivors ~1230 +/- 280
  if (avail < CAP) CAP = (int)avail;
  if (CAP < 256) CAP = 256;
  const int M = (N < 16384) ? N : 16384;
  const int RANK = 16;
  const float MARGIN = 0.25f;
  const int ntiles = (N + 15) >> 4;

  k_sample<<<B, 256, 0, stream>>>(user, corpus, thr, cnt, ubf, M, RANK);
  k_filter<<<FIL_BLOCKS, 256, 0, stream>>>(corpus, ubf, thr, cnt, cand, N, CAP, ntiles, MARGIN);
  k_rescore<<<B * 4, 256, 0, stream>>>(user, corpus, cnt, cand, CAP);
  k_select<<<B, 256, 0, stream>>>(cand, cnt, out, B, CAP);
}

// Round 9
// 249.803 us; speedup vs baseline: 2.4550x; 1.5650x over previous
//
#include <hip/hip_runtime.h>
#include <stdint.h>

#define TOPK 100
#define GCAP 2048
#define FIL_BLOCKS 1024
#define SLIST_CAP 2048

typedef __attribute__((ext_vector_type(8))) short bf16x8;
typedef __attribute__((ext_vector_type(4))) float f32x4;

__device__ __forceinline__ unsigned int fsort(float f) {
  unsigned int u = __float_as_uint(f);
  return (u & 0x80000000u) ? ~u : (u | 0x80000000u);
}
__device__ __forceinline__ float funsort(unsigned int k) {
  unsigned int u = (k & 0x80000000u) ? (k ^ 0x80000000u) : ~k;
  return __uint_as_float(u);
}
__device__ __forceinline__ unsigned short f2bf(float f) {
  unsigned int u = __float_as_uint(f);
  unsigned int r = (u + 0x7fffu + ((u >> 16) & 1u)) >> 16;  // RNE
  return (unsigned short)r;
}

// cnt is padded: user u's counter lives at cnt[u*16] (64 B apart).

// ------- Kernel 0: bf16 user panel ---------------------------------------
__global__ void k_prep(const float* __restrict__ user,
                       unsigned short* __restrict__ ubf, int n) {
  const int i = blockIdx.x * blockDim.x + threadIdx.x;
  if (i < n) ubf[i] = f2bf(user[i]);
}

// ------- Kernel 1a: MFMA sample scores (first M rows, ALL users) ----------
// Same wave structure as k_filter; one 16-row tile per wave; writes
// sc[user*M + row] as per-lane float4 (4 consecutive rows).
__global__ __launch_bounds__(256, 2) void k_sscore(
    const float* __restrict__ corpus,
    const unsigned short* __restrict__ ubf,
    float* __restrict__ sc,
    int M) {
  const int t = threadIdx.x;
  const int lane = t & 63;
  const int wave = t >> 6;
  const int l15 = lane & 15;
  const int l4  = lane >> 4;

  bf16x8 bf[16][2];
#pragma unroll
  for (int ut = 0; ut < 16; ++ut) {
    const int uu = ut * 16 + l15;
#pragma unroll
    for (int kh = 0; kh < 2; ++kh)
      bf[ut][kh] = *(const bf16x8*)(ubf + uu * 64 + kh * 32 + l4 * 8);
  }

  const int ntiles_s = M >> 4;
  const int stride = gridDim.x * 4;
  for (int tile = blockIdx.x * 4 + wave; tile < ntiles_s; tile += stride) {
    const int rb = tile << 4;
    const long long rowc = (long long)(rb + l15);
    const float4* rp = (const float4*)(corpus + rowc * 64);
    float4 c00 = rp[l4 * 2 + 0];
    float4 c01 = rp[l4 * 2 + 1];
    float4 c10 = rp[8 + l4 * 2 + 0];
    float4 c11 = rp[8 + l4 * 2 + 1];

    bf16x8 af0, af1;
    af0[0] = (short)f2bf(c00.x); af0[1] = (short)f2bf(c00.y);
    af0[2] = (short)f2bf(c00.z); af0[3] = (short)f2bf(c00.w);
    af0[4] = (short)f2bf(c01.x); af0[5] = (short)f2bf(c01.y);
    af0[6] = (short)f2bf(c01.z); af0[7] = (short)f2bf(c01.w);
    af1[0] = (short)f2bf(c10.x); af1[1] = (short)f2bf(c10.y);
    af1[2] = (short)f2bf(c10.z); af1[3] = (short)f2bf(c10.w);
    af1[4] = (short)f2bf(c11.x); af1[5] = (short)f2bf(c11.y);
    af1[6] = (short)f2bf(c11.z); af1[7] = (short)f2bf(c11.w);

#pragma unroll
    for (int ut = 0; ut < 16; ++ut) {
      f32x4 acc = (f32x4){0.f, 0.f, 0.f, 0.f};
      acc = __builtin_amdgcn_mfma_f32_16x16x32_bf16(af0, bf[ut][0], acc, 0, 0, 0);
      acc = __builtin_amdgcn_mfma_f32_16x16x32_bf16(af1, bf[ut][1], acc, 0, 0, 0);
      const int uu = ut * 16 + l15;
      *(float4*)(sc + (size_t)uu * M + rb + l4 * 4) =
          (float4){acc[0], acc[1], acc[2], acc[3]};
    }
  }
}

// ------- Kernel 1b: per-user threshold from sample scores + cnt zero ------
__global__ void k_thresh(const float* __restrict__ sc,
                         float* __restrict__ thr,
                         unsigned int* __restrict__ cnt,
                         int M, int rank) {
  __shared__ float s_scores[16384];
  __shared__ unsigned int s_hist[256];
  __shared__ float s_wred[8];
  __shared__ float s_bmax, s_bmin;

  const int u = blockIdx.x;
  const int t = threadIdx.x;
  if (t == 0) cnt[u * 16] = 0u;

  float lmax = -3.0e38f, lmin = 3.0e38f;
  for (int i = t; i < M; i += 256) {
    float v = sc[(size_t)u * M + i];     // coalesced
    s_scores[i] = v;
    lmax = fmaxf(lmax, v);
    lmin = fminf(lmin, v);
  }
#pragma unroll
  for (int o = 32; o > 0; o >>= 1) {
    lmax = fmaxf(lmax, __shfl_down(lmax, o));
    lmin = fminf(lmin, __shfl_down(lmin, o));
  }
  if ((t & 63) == 0) { s_wred[t >> 6] = lmax; s_wred[4 + (t >> 6)] = lmin; }
  s_hist[t] = 0u;
  __syncthreads();
  if (t == 0) {
    float bm = s_wred[0], bn = s_wred[4];
    for (int w = 1; w < 4; ++w) { bm = fmaxf(bm, s_wred[w]); bn = fminf(bn, s_wred[4 + w]); }
    s_bmax = bm; s_bmin = bn;
  }
  __syncthreads();
  const float bmax = s_bmax, bmin = s_bmin;
  const float width = (bmax - bmin) / 256.0f;
  const float inv = (width > 0.f) ? 1.0f / width : 0.f;
  for (int i = t; i < M; i += 256) {
    int b = (int)((s_scores[i] - bmin) * inv);
    b = min(max(b, 0), 255);
    atomicAdd(&s_hist[b], 1u);
  }
  __syncthreads();
  if (t == 0) {
    unsigned int cum = 0;
    int b = 255;
    for (; b >= 0; --b) { cum += s_hist[b]; if (cum >= (unsigned int)rank) break; }
    if (b < 0) b = 0;
    thr[u] = bmin + width * (float)b;    // lower edge: conservative
  }
}

// ------- Kernel 2: MFMA bf16 filter — one tile per WAVE, LDS-staged -------
__global__ __launch_bounds__(256, 2) void k_filter(
    const float* __restrict__ corpus,
    const unsigned short* __restrict__ ubf,
    const float* __restrict__ thr,
    unsigned int* __restrict__ cnt,
    unsigned long long* __restrict__ cand,
    int N, int CAP, int ntiles, float margin) {
  __shared__ unsigned int slist[SLIST_CAP];
  __shared__ unsigned int scnt;

  const int t = threadIdx.x;
  const int lane = t & 63;
  const int wave = t >> 6;
  const int l15 = lane & 15;
  const int l4  = lane >> 4;

  if (t == 0) scnt = 0u;
  __syncthreads();

  bf16x8 bf[16][2];
  float thv[16];
#pragma unroll
  for (int ut = 0; ut < 16; ++ut) {
    const int uu = ut * 16 + l15;
#pragma unroll
    for (int kh = 0; kh < 2; ++kh)
      bf[ut][kh] = *(const bf16x8*)(ubf + uu * 64 + kh * 32 + l4 * 8);
    thv[ut] = thr[uu] - margin;
  }

  const int stride = FIL_BLOCKS * 4;
  int tile = blockIdx.x * 4 + wave;

  if (tile < ntiles) {
    long long rowc = (long long)min(tile * 16 + l15, N - 1);
    const float4* rp = (const float4*)(corpus + rowc * 64);
    float4 c00 = rp[l4 * 2 + 0];
    float4 c01 = rp[l4 * 2 + 1];
    float4 c10 = rp[8 + l4 * 2 + 0];
    float4 c11 = rp[8 + l4 * 2 + 1];

    for (;;) {
      const int next = tile + stride;
      const bool have_next = (next < ntiles);
      float4 n00, n01, n10, n11;
      if (have_next) {
        long long rowc2 = (long long)min(next * 16 + l15, N - 1);
        const float4* rp2 = (const float4*)(corpus + rowc2 * 64);
        n00 = rp2[l4 * 2 + 0];
        n01 = rp2[l4 * 2 + 1];
        n10 = rp2[8 + l4 * 2 + 0];
        n11 = rp2[8 + l4 * 2 + 1];
      }

      bf16x8 af0, af1;
      af0[0] = (short)f2bf(c00.x); af0[1] = (short)f2bf(c00.y);
      af0[2] = (short)f2bf(c00.z); af0[3] = (short)f2bf(c00.w);
      af0[4] = (short)f2bf(c01.x); af0[5] = (short)f2bf(c01.y);
      af0[6] = (short)f2bf(c01.z); af0[7] = (short)f2bf(c01.w);
      af1[0] = (short)f2bf(c10.x); af1[1] = (short)f2bf(c10.y);
      af1[2] = (short)f2bf(c10.z); af1[3] = (short)f2bf(c10.w);
      af1[4] = (short)f2bf(c11.x); af1[5] = (short)f2bf(c11.y);
      af1[6] = (short)f2bf(c11.z); af1[7] = (short)f2bf(c11.w);

      const int rb = tile << 4;
#pragma unroll
      for (int ut = 0; ut < 16; ++ut) {
        f32x4 acc = (f32x4){0.f, 0.f, 0.f, 0.f};
        acc = __builtin_amdgcn_mfma_f32_16x16x32_bf16(af0, bf[ut][0], acc, 0, 0, 0);
        acc = __builtin_amdgcn_mfma_f32_16x16x32_bf16(af1, bf[ut][1], acc, 0, 0, 0);
        bool hit = (acc[0] >= thv[ut]) | (acc[1] >= thv[ut]) |
                   (acc[2] >= thv[ut]) | (acc[3] >= thv[ut]);
        if (__ballot(hit)) {
          const unsigned int uu = (unsigned int)(ut * 16 + l15);
#pragma unroll
          for (int r = 0; r < 4; ++r) {
            const int row = rb + l4 * 4 + r;
            if (acc[r] >= thv[ut] && row < N) {
              unsigned int pos = atomicAdd(&scnt, 1u);
              if (pos < SLIST_CAP) {
                slist[pos] = (uu << 20) | (unsigned int)row;
              } else {  // fallback: direct global append
                unsigned int gp = atomicAdd(&cnt[uu * 16], 1u);
                if (gp < (unsigned int)CAP)
                  cand[(size_t)uu * (size_t)CAP + gp] = (unsigned long long)(unsigned int)row;
              }
            }
          }
        }
      }

      if (!have_next) break;
      tile = next;
      c00 = n00; c01 = n01; c10 = n10; c11 = n11;
    }
  }

  __syncthreads();
  // flush: thread t owns user t; two broadcast scans
  const int n = min((int)scnt, SLIST_CAP);
  const unsigned int me = (unsigned int)t;
  unsigned int c = 0;
  for (int i = 0; i < n; ++i)
    if ((slist[i] >> 20) == me) ++c;
  unsigned int base = 0;
  if (c) base = atomicAdd(&cnt[me * 16], c);
  if (c) {
    unsigned int k = 0;
    for (int i = 0; i < n; ++i) {
      unsigned int v = slist[i];
      if ((v >> 20) == me) {
        unsigned int p = base + k;
        if (p < (unsigned int)CAP)
          cand[(size_t)me * (size_t)CAP + p] = (unsigned long long)(v & 0xFFFFFu);
        ++k;
      }
    }
  }
}

// ------- Kernel 3: exact fp32 rescore of survivors ------------------------
__global__ void k_rescore(const float* __restrict__ user,
                          const float* __restrict__ corpus,
                          const unsigned int* __restrict__ cnt,
                          unsigned long long* __restrict__ cand,
                          int CAP) {
  __shared__ float su[64];
  const int u = blockIdx.x >> 2;
  const int q = blockIdx.x & 3;
  const int t = threadIdx.x;
  if (t < 64) su[t] = user[u * 64 + t];
  __syncthreads();
  float uv[64];
#pragma unroll
  for (int i = 0; i < 64; ++i) uv[i] = su[i];
  const int n = min((int)cnt[u * 16], CAP);
  for (int i = q * 256 + t; i < n; i += 1024) {
    const unsigned int row = (unsigned int)cand[(size_t)u * (size_t)CAP + i];
    const float4* rp = (const float4*)(corpus + (size_t)row * 64);
    float acc = 0.f;
#pragma unroll
    for (int k = 0; k < 16; ++k) {
      float4 c = rp[k];
      acc = fmaf(uv[4*k+0], c.x, acc);
      acc = fmaf(uv[4*k+1], c.y, acc);
      acc = fmaf(uv[4*k+2], c.z, acc);
      acc = fmaf(uv[4*k+3], c.w, acc);
    }
    cand[(size_t)u * (size_t)CAP + i] = ((unsigned long long)fsort(acc) << 32)
                                      | (unsigned long long)(~row);
  }
}

// ------- Kernel 4: exact top-100 per user ---------------------------------
__global__ void k_select(const unsigned long long* __restrict__ cand,
                         const unsigned int* __restrict__ cnt,
                         float* __restrict__ out,
                         int B, int CAP) {
  __shared__ unsigned long long keys[GCAP];
  __shared__ unsigned int hist[1024];
  __shared__ unsigned int s_kmax, s_kmin, s_gcnt;
  __shared__ int s_bstar;

  const int u = blockIdx.x;
  const int t = threadIdx.x;
  const int n = min((int)cnt[u * 16], CAP);
  const unsigned long long* cu = cand + (size_t)u * (size_t)CAP;

  if (t == 0) { s_kmax = 0u; s_kmin = 0xFFFFFFFFu; s_gcnt = 0u; }
  for (int i = t; i < 1024; i += 256) hist[i] = 0u;
  __syncthreads();

  unsigned int lmax = 0u, lmin = 0xFFFFFFFFu;
  for (int i = t; i < n; i += 256) {
    unsigned int k = (unsigned int)(cu[i] >> 32);
    lmax = max(lmax, k); lmin = min(lmin, k);
  }
#pragma unroll
  for (int o = 32; o > 0; o >>= 1) {
    lmax = max(lmax, __shfl_down(lmax, o));
    lmin = min(lmin, __shfl_down(lmin, o));
  }
  if ((t & 63) == 0) { atomicMax(&s_kmax, lmax); atomicMin(&s_kmin, lmin); }
  __syncthreads();
  const unsigned int kmax = s_kmax, kmin = s_kmin;
  const unsigned long long range = (unsigned long long)(kmax - kmin) + 1ull;

  for (int i = t; i < n; i += 256) {
    unsigned int k = (unsigned int)(cu[i] >> 32);
    unsigned int b = (unsigned int)((((unsigned long long)(k - kmin)) << 10) / range);
    atomicAdd(&hist[min(b, 1023u)], 1u);
  }
  __syncthreads();
  if (t == 0) {
    unsigned int cum = 0;
    int b = 1023;
    for (; b >= 0; --b) { cum += hist[b]; if (cum >= TOPK) break; }
    s_bstar = (b < 0) ? 0 : b;
  }
  __syncthreads();
  const unsigned int bstar = (unsigned int)s_bstar;

  for (int i = t; i < n; i += 256) {
    unsigned long long key = cu[i];
    unsigned int k = (unsigned int)(key >> 32);
    unsigned int b = min((unsigned int)((((unsigned long long)(k - kmin)) << 10) / range), 1023u);
    if (b >= bstar) {
      unsigned int pos = atomicAdd(&s_gcnt, 1u);
      if (pos < GCAP) keys[pos] = key;
    }
  }
  __syncthreads();
  const int g = min((int)s_gcnt, GCAP);
  int S = 128;
  while (S < g) S <<= 1;
  for (int i = g + t; i < S; i += 256) keys[i] = 0ull;
  __syncthreads();

  for (int k = 2; k <= S; k <<= 1) {
    for (int j = k >> 1; j > 0; j >>= 1) {
      for (int i = t; i < S; i += 256) {
        int ixj = i ^ j;
        if (ixj > i) {
          unsigned long long a = keys[i], b2 = keys[ixj];
          bool descSeg = ((i & k) == 0);
          bool sw = descSeg ? (a < b2) : (a > b2);
          if (sw) { keys[i] = b2; keys[ixj] = a; }
        }
      }
      __syncthreads();
    }
  }

  if (t < TOPK) {
    unsigned long long key = keys[t];
    unsigned int kk = (unsigned int)(key >> 32);
    unsigned int idx = ~(unsigned int)(key & 0xFFFFFFFFull);
    out[u * TOPK + t] = funsort(kk);
    out[(size_t)B * TOPK + u * TOPK + t] = (float)idx;
  }
}

extern "C" void kernel_launch(void* const* d_in, const int* in_sizes, int n_in,
                              void* d_out, int out_size, void* d_ws, size_t ws_size,
                              hipStream_t stream) {
  const float* user = (const float*)d_in[0];
  const float* corpus = (const float*)d_in[1];
  float* out = (float*)d_out;
  const int B = in_sizes[0] / 64;           // 256
  const int N = in_sizes[1] / 64;           // 1,000,000

  // ws: cnt_pad[B*16] u32 @0 (16 KB) | thr[B] f32 @16384 | ubf[B*64] u16 @17408
  //     | sc f32 [B*M] @50176 | cand u64 after sc
  unsigned int* cnt = (unsigned int*)d_ws;
  float* thr = (float*)((char*)d_ws + 16384);
  unsigned short* ubf = (unsigned short*)((char*)d_ws + 17408);
  const size_t sc_off = 50176;

  int CAP = 4096;                    // survivors ~1100 +/- 280
  long long M = 16384;
  long long need = (long long)sc_off + M * B * 4 + (long long)B * CAP * 8;
  if ((long long)ws_size < need) {   // degrade M first (1 KB per row), then CAP
    long long spare = (long long)ws_size - sc_off - (long long)B * CAP * 8;
    M = (spare / (B * 4)) & ~1023LL;
    if (M < 4096) {
      M = 4096;
      long long spare2 = (long long)ws_size - sc_off - M * B * 4;
      CAP = (int)(spare2 / ((long long)B * 8));
      if (CAP < 256) CAP = 256;
    }
  }
  if (M > (long long)N) M = (long long)(N & ~1023);
  float* sc = (float*)((char*)d_ws + sc_off);
  unsigned long long* cand = (unsigned long long*)((char*)d_ws + sc_off + (size_t)(M * B * 4));

  const int RANK = (int)(M >> 10);          // 16 @ M=16384
  const float MARGIN = 0.25f;
  const int ntiles = (N + 15) >> 4;

  k_prep<<<(B * 64 + 255) / 256, 256, 0, stream>>>(user, ubf, B * 64);
  k_sscore<<<256, 256, 0, stream>>>(corpus, ubf, sc, (int)M);
  k_thresh<<<B, 256, 0, stream>>>(sc, thr, cnt, (int)M, RANK);
  k_filter<<<FIL_BLOCKS, 256, 0, stream>>>(corpus, ubf, thr, cnt, cand, N, CAP, ntiles, MARGIN);
  k_rescore<<<B * 4, 256, 0, stream>>>(user, corpus, cnt, cand, CAP);
  k_select<<<B, 256, 0, stream>>>(cand, cnt, out, B, CAP);
}

// Round 10
// 248.540 us; speedup vs baseline: 2.4675x; 1.0051x over previous
//
#include <hip/hip_runtime.h>
#include <stdint.h>

#define TOPK 100
#define GCAP 2048
#define FIL_BLOCKS 1024
#define SLIST_CAP 2048

typedef __attribute__((ext_vector_type(8))) short bf16x8;
typedef __attribute__((ext_vector_type(4))) float f32x4;

__device__ __forceinline__ unsigned int fsort(float f) {
  unsigned int u = __float_as_uint(f);
  return (u & 0x80000000u) ? ~u : (u | 0x80000000u);
}
__device__ __forceinline__ float funsort(unsigned int k) {
  unsigned int u = (k & 0x80000000u) ? (k ^ 0x80000000u) : ~k;
  return __uint_as_float(u);
}
__device__ __forceinline__ unsigned short f2bf(float f) {
  unsigned int u = __float_as_uint(f);
  unsigned int r = (u + 0x7fffu + ((u >> 16) & 1u)) >> 16;  // RNE
  return (unsigned short)r;
}
__device__ __forceinline__ bf16x8 pack_bf(const float4& a, const float4& b) {
  bf16x8 r;
  r[0] = (short)f2bf(a.x); r[1] = (short)f2bf(a.y);
  r[2] = (short)f2bf(a.z); r[3] = (short)f2bf(a.w);
  r[4] = (short)f2bf(b.x); r[5] = (short)f2bf(b.y);
  r[6] = (short)f2bf(b.z); r[7] = (short)f2bf(b.w);
  return r;
}

// cnt is padded: user u's counter lives at cnt[u*16] (64 B apart).

// ------- Kernel 0: bf16 user panel ---------------------------------------
__global__ void k_prep(const float* __restrict__ user,
                       unsigned short* __restrict__ ubf, int n) {
  const int i = blockIdx.x * blockDim.x + threadIdx.x;
  if (i < n) ubf[i] = f2bf(user[i]);
}

// ------- Kernel 1a: MFMA sample scores (first M rows, ALL users) ----------
// Wave pair shares a tile stream: wave&1 selects the 128-user half (8 ut
// frags = 64 VGPR), wave>>1 selects the stream. Second tile read hits L1/L2.
__global__ __launch_bounds__(256, 2) void k_sscore(
    const float* __restrict__ corpus,
    const unsigned short* __restrict__ ubf,
    float* __restrict__ sc,
    int M) {
  const int t = threadIdx.x;
  const int lane = t & 63;
  const int wave = t >> 6;
  const int l15 = lane & 15;
  const int l4  = lane >> 4;
  const int ubase = (wave & 1) * 128;

  bf16x8 bf[8][2];
#pragma unroll
  for (int ut = 0; ut < 8; ++ut) {
    const int uu = ubase + ut * 16 + l15;
#pragma unroll
    for (int kh = 0; kh < 2; ++kh)
      bf[ut][kh] = *(const bf16x8*)(ubf + uu * 64 + kh * 32 + l4 * 8);
  }

  const int ntiles_s = M >> 4;
  const int stride = gridDim.x * 2;
  for (int tile = blockIdx.x * 2 + (wave >> 1); tile < ntiles_s; tile += stride) {
    const int rb = tile << 4;
    const float4* rp = (const float4*)(corpus + (long long)(rb + l15) * 64);
    float4 a0 = rp[l4 * 2 + 0];
    float4 a1 = rp[l4 * 2 + 1];
    float4 a2 = rp[8 + l4 * 2 + 0];
    float4 a3 = rp[8 + l4 * 2 + 1];
    bf16x8 af0 = pack_bf(a0, a1);
    bf16x8 af1 = pack_bf(a2, a3);

#pragma unroll
    for (int ut = 0; ut < 8; ++ut) {
      f32x4 acc = (f32x4){0.f, 0.f, 0.f, 0.f};
      acc = __builtin_amdgcn_mfma_f32_16x16x32_bf16(af0, bf[ut][0], acc, 0, 0, 0);
      acc = __builtin_amdgcn_mfma_f32_16x16x32_bf16(af1, bf[ut][1], acc, 0, 0, 0);
      const int uu = ubase + ut * 16 + l15;
      *(float4*)(sc + (size_t)uu * M + rb + l4 * 4) =
          (float4){acc[0], acc[1], acc[2], acc[3]};
    }
  }
}

// ------- Kernel 1b: per-user threshold from sample scores + cnt zero ------
__global__ void k_thresh(const float* __restrict__ sc,
                         float* __restrict__ thr,
                         unsigned int* __restrict__ cnt,
                         int M, int rank) {
  __shared__ float s_scores[16384];
  __shared__ unsigned int s_hist[256];
  __shared__ float s_wred[8];
  __shared__ float s_bmax, s_bmin;

  const int u = blockIdx.x;
  const int t = threadIdx.x;
  if (t == 0) cnt[u * 16] = 0u;

  float lmax = -3.0e38f, lmin = 3.0e38f;
  for (int i = t; i < M; i += 256) {
    float v = sc[(size_t)u * M + i];     // coalesced
    s_scores[i] = v;
    lmax = fmaxf(lmax, v);
    lmin = fminf(lmin, v);
  }
#pragma unroll
  for (int o = 32; o > 0; o >>= 1) {
    lmax = fmaxf(lmax, __shfl_down(lmax, o));
    lmin = fminf(lmin, __shfl_down(lmin, o));
  }
  if ((t & 63) == 0) { s_wred[t >> 6] = lmax; s_wred[4 + (t >> 6)] = lmin; }
  s_hist[t] = 0u;
  __syncthreads();
  if (t == 0) {
    float bm = s_wred[0], bn = s_wred[4];
    for (int w = 1; w < 4; ++w) { bm = fmaxf(bm, s_wred[w]); bn = fminf(bn, s_wred[4 + w]); }
    s_bmax = bm; s_bmin = bn;
  }
  __syncthreads();
  const float bmax = s_bmax, bmin = s_bmin;
  const float width = (bmax - bmin) / 256.0f;
  const float inv = (width > 0.f) ? 1.0f / width : 0.f;
  for (int i = t; i < M; i += 256) {
    int b = (int)((s_scores[i] - bmin) * inv);
    b = min(max(b, 0), 255);
    atomicAdd(&s_hist[b], 1u);
  }
  __syncthreads();
  if (t == 0) {
    unsigned int cum = 0;
    int b = 255;
    for (; b >= 0; --b) { cum += s_hist[b]; if (cum >= (unsigned int)rank) break; }
    if (b < 0) b = 0;
    thr[u] = bmin + width * (float)b;    // lower edge: conservative
  }
}

// ------- Kernel 2: MFMA bf16 filter — 8 ut/wave, wave-pair tile sharing ----
// Register budget ~115 (<128): bf frags 64, thv 8, af 8, raw-next 16, misc.
// Prefetch next tile's raw f32 during compute; convert once after.
__global__ __launch_bounds__(256, 2) void k_filter(
    const float* __restrict__ corpus,
    const unsigned short* __restrict__ ubf,
    const float* __restrict__ thr,
    unsigned int* __restrict__ cnt,
    unsigned long long* __restrict__ cand,
    int N, int CAP, int ntiles, float margin) {
  __shared__ unsigned int slist[SLIST_CAP];
  __shared__ unsigned int scnt;

  const int t = threadIdx.x;
  const int lane = t & 63;
  const int wave = t >> 6;
  const int l15 = lane & 15;
  const int l4  = lane >> 4;
  const int ubase = (wave & 1) * 128;

  if (t == 0) scnt = 0u;
  __syncthreads();

  bf16x8 bf[8][2];
  float thv[8];
#pragma unroll
  for (int ut = 0; ut < 8; ++ut) {
    const int uu = ubase + ut * 16 + l15;
#pragma unroll
    for (int kh = 0; kh < 2; ++kh)
      bf[ut][kh] = *(const bf16x8*)(ubf + uu * 64 + kh * 32 + l4 * 8);
    thv[ut] = thr[uu] - margin;
  }

  const int stride = FIL_BLOCKS * 2;
  int tile = blockIdx.x * 2 + (wave >> 1);

  if (tile < ntiles) {
    // prologue: load + convert first tile
    const float4* rp = (const float4*)(corpus + (long long)min(tile * 16 + l15, N - 1) * 64);
    bf16x8 af0, af1;
    {
      float4 a0 = rp[l4 * 2 + 0];
      float4 a1 = rp[l4 * 2 + 1];
      float4 a2 = rp[8 + l4 * 2 + 0];
      float4 a3 = rp[8 + l4 * 2 + 1];
      af0 = pack_bf(a0, a1);
      af1 = pack_bf(a2, a3);
    }

    for (;;) {
      const int next = tile + stride;
      const bool have_next = (next < ntiles);
      float4 n0, n1, n2, n3;
      if (have_next) {                     // prefetch raw f32 (hidden by compute)
        const float4* rp2 = (const float4*)(corpus + (long long)min(next * 16 + l15, N - 1) * 64);
        n0 = rp2[l4 * 2 + 0];
        n1 = rp2[l4 * 2 + 1];
        n2 = rp2[8 + l4 * 2 + 0];
        n3 = rp2[8 + l4 * 2 + 1];
      }

      const int rb = tile << 4;
#pragma unroll
      for (int ut = 0; ut < 8; ++ut) {
        f32x4 acc = (f32x4){0.f, 0.f, 0.f, 0.f};
        acc = __builtin_amdgcn_mfma_f32_16x16x32_bf16(af0, bf[ut][0], acc, 0, 0, 0);
        acc = __builtin_amdgcn_mfma_f32_16x16x32_bf16(af1, bf[ut][1], acc, 0, 0, 0);
        bool hit = (acc[0] >= thv[ut]) | (acc[1] >= thv[ut]) |
                   (acc[2] >= thv[ut]) | (acc[3] >= thv[ut]);
        if (__ballot(hit)) {
          const unsigned int uu = (unsigned int)(ubase + ut * 16 + l15);
#pragma unroll
          for (int r = 0; r < 4; ++r) {
            const int row = rb + l4 * 4 + r;
            if (acc[r] >= thv[ut] && row < N) {
              unsigned int pos = atomicAdd(&scnt, 1u);
              if (pos < SLIST_CAP) {
                slist[pos] = (uu << 20) | (unsigned int)row;
              } else {  // fallback: direct global append
                unsigned int gp = atomicAdd(&cnt[uu * 16], 1u);
                if (gp < (unsigned int)CAP)
                  cand[(size_t)uu * (size_t)CAP + gp] = (unsigned long long)(unsigned int)row;
              }
            }
          }
        }
      }

      if (!have_next) break;
      af0 = pack_bf(n0, n1);               // convert once; raw regs die here
      af1 = pack_bf(n2, n3);
      tile = next;
    }
  }

  __syncthreads();
  // flush: thread t owns user t; two broadcast scans
  const int n = min((int)scnt, SLIST_CAP);
  const unsigned int me = (unsigned int)t;
  unsigned int c = 0;
  for (int i = 0; i < n; ++i)
    if ((slist[i] >> 20) == me) ++c;
  unsigned int base = 0;
  if (c) base = atomicAdd(&cnt[me * 16], c);
  if (c) {
    unsigned int k = 0;
    for (int i = 0; i < n; ++i) {
      unsigned int v = slist[i];
      if ((v >> 20) == me) {
        unsigned int p = base + k;
        if (p < (unsigned int)CAP)
          cand[(size_t)me * (size_t)CAP + p] = (unsigned long long)(v & 0xFFFFFu);
        ++k;
      }
    }
  }
}

// ------- Kernel 3: exact fp32 rescore of survivors ------------------------
__global__ void k_rescore(const float* __restrict__ user,
                          const float* __restrict__ corpus,
                          const unsigned int* __restrict__ cnt,
                          unsigned long long* __restrict__ cand,
                          int CAP) {
  __shared__ float su[64];
  const int u = blockIdx.x >> 2;
  const int q = blockIdx.x & 3;
  const int t = threadIdx.x;
  if (t < 64) su[t] = user[u * 64 + t];
  __syncthreads();
  float uv[64];
#pragma unroll
  for (int i = 0; i < 64; ++i) uv[i] = su[i];
  const int n = min((int)cnt[u * 16], CAP);
  for (int i = q * 256 + t; i < n; i += 1024) {
    const unsigned int row = (unsigned int)cand[(size_t)u * (size_t)CAP + i];
    const float4* rp = (const float4*)(corpus + (size_t)row * 64);
    float acc = 0.f;
#pragma unroll
    for (int k = 0; k < 16; ++k) {
      float4 c = rp[k];
      acc = fmaf(uv[4*k+0], c.x, acc);
      acc = fmaf(uv[4*k+1], c.y, acc);
      acc = fmaf(uv[4*k+2], c.z, acc);
      acc = fmaf(uv[4*k+3], c.w, acc);
    }
    cand[(size_t)u * (size_t)CAP + i] = ((unsigned long long)fsort(acc) << 32)
                                      | (unsigned long long)(~row);
  }
}

// ------- Kernel 4: exact top-100 per user ---------------------------------
__global__ void k_select(const unsigned long long* __restrict__ cand,
                         const unsigned int* __restrict__ cnt,
                         float* __restrict__ out,
                         int B, int CAP) {
  __shared__ unsigned long long keys[GCAP];
  __shared__ unsigned int hist[1024];
  __shared__ unsigned int s_kmax, s_kmin, s_gcnt;
  __shared__ int s_bstar;

  const int u = blockIdx.x;
  const int t = threadIdx.x;
  const int n = min((int)cnt[u * 16], CAP);
  const unsigned long long* cu = cand + (size_t)u * (size_t)CAP;

  if (t == 0) { s_kmax = 0u; s_kmin = 0xFFFFFFFFu; s_gcnt = 0u; }
  for (int i = t; i < 1024; i += 256) hist[i] = 0u;
  __syncthreads();

  unsigned int lmax = 0u, lmin = 0xFFFFFFFFu;
  for (int i = t; i < n; i += 256) {
    unsigned int k = (unsigned int)(cu[i] >> 32);
    lmax = max(lmax, k); lmin = min(lmin, k);
  }
#pragma unroll
  for (int o = 32; o > 0; o >>= 1) {
    lmax = max(lmax, __shfl_down(lmax, o));
    lmin = min(lmin, __shfl_down(lmin, o));
  }
  if ((t & 63) == 0) { atomicMax(&s_kmax, lmax); atomicMin(&s_kmin, lmin); }
  __syncthreads();
  const unsigned int kmax = s_kmax, kmin = s_kmin;
  const unsigned long long range = (unsigned long long)(kmax - kmin) + 1ull;

  for (int i = t; i < n; i += 256) {
    unsigned int k = (unsigned int)(cu[i] >> 32);
    unsigned int b = (unsigned int)((((unsigned long long)(k - kmin)) << 10) / range);
    atomicAdd(&hist[min(b, 1023u)], 1u);
  }
  __syncthreads();
  if (t == 0) {
    unsigned int cum = 0;
    int b = 1023;
    for (; b >= 0; --b) { cum += hist[b]; if (cum >= TOPK) break; }
    s_bstar = (b < 0) ? 0 : b;
  }
  __syncthreads();
  const unsigned int bstar = (unsigned int)s_bstar;

  for (int i = t; i < n; i += 256) {
    unsigned long long key = cu[i];
    unsigned int k = (unsigned int)(key >> 32);
    unsigned int b = min((unsigned int)((((unsigned long long)(k - kmin)) << 10) / range), 1023u);
    if (b >= bstar) {
      unsigned int pos = atomicAdd(&s_gcnt, 1u);
      if (pos < GCAP) keys[pos] = key;
    }
  }
  __syncthreads();
  const int g = min((int)s_gcnt, GCAP);
  int S = 128;
  while (S < g) S <<= 1;
  for (int i = g + t; i < S; i += 256) keys[i] = 0ull;
  __syncthreads();

  for (int k = 2; k <= S; k <<= 1) {
    for (int j = k >> 1; j > 0; j >>= 1) {
      for (int i = t; i < S; i += 256) {
        int ixj = i ^ j;
        if (ixj > i) {
          unsigned long long a = keys[i], b2 = keys[ixj];
          bool descSeg = ((i & k) == 0);
          bool sw = descSeg ? (a < b2) : (a > b2);
          if (sw) { keys[i] = b2; keys[ixj] = a; }
        }
      }
      __syncthreads();
    }
  }

  if (t < TOPK) {
    unsigned long long key = keys[t];
    unsigned int kk = (unsigned int)(key >> 32);
    unsigned int idx = ~(unsigned int)(key & 0xFFFFFFFFull);
    out[u * TOPK + t] = funsort(kk);
    out[(size_t)B * TOPK + u * TOPK + t] = (float)idx;
  }
}

extern "C" void kernel_launch(void* const* d_in, const int* in_sizes, int n_in,
                              void* d_out, int out_size, void* d_ws, size_t ws_size,
                              hipStream_t stream) {
  const float* user = (const float*)d_in[0];
  const float* corpus = (const float*)d_in[1];
  float* out = (float*)d_out;
  const int B = in_sizes[0] / 64;           // 256
  const int N = in_sizes[1] / 64;           // 1,000,000

  // ws: cnt_pad[B*16] u32 @0 (16 KB) | thr[B] f32 @16384 | ubf[B*64] u16 @17408
  //     | sc f32 [B*M] @50176 | cand u64 after sc
  unsigned int* cnt = (unsigned int*)d_ws;
  float* thr = (float*)((char*)d_ws + 16384);
  unsigned short* ubf = (unsigned short*)((char*)d_ws + 17408);
  const size_t sc_off = 50176;

  int CAP = 4096;                    // survivors ~1100 +/- 280
  long long M = 16384;
  long long need = (long long)sc_off + M * B * 4 + (long long)B * CAP * 8;
  if ((long long)ws_size < need) {   // degrade M first (1 KB per row), then CAP
    long long spare = (long long)ws_size - sc_off - (long long)B * CAP * 8;
    M = (spare / (B * 4)) & ~1023LL;
    if (M < 4096) {
      M = 4096;
      long long spare2 = (long long)ws_size - sc_off - M * B * 4;
      CAP = (int)(spare2 / ((long long)B * 8));
      if (CAP < 256) CAP = 256;
    }
  }
  if (M > (long long)N) M = (long long)(N & ~1023);
  float* sc = (float*)((char*)d_ws + sc_off);
  unsigned long long* cand = (unsigned long long*)((char*)d_ws + sc_off + (size_t)(M * B * 4));

  const int RANK = (int)(M >> 10);          // 16 @ M=16384
  const float MARGIN = 0.25f;
  const int ntiles = (N + 15) >> 4;

  k_prep<<<(B * 64 + 255) / 256, 256, 0, stream>>>(user, ubf, B * 64);
  k_sscore<<<256, 256, 0, stream>>>(corpus, ubf, sc, (int)M);
  k_thresh<<<B, 256, 0, stream>>>(sc, thr, cnt, (int)M, RANK);
  k_filter<<<FIL_BLOCKS, 256, 0, stream>>>(corpus, ubf, thr, cnt, cand, N, CAP, ntiles, MARGIN);
  k_rescore<<<B * 4, 256, 0, stream>>>(user, corpus, cnt, cand, CAP);
  k_select<<<B, 256, 0, stream>>>(cand, cnt, out, B, CAP);
}

// Round 11
// 238.729 us; speedup vs baseline: 2.5689x; 1.0411x over previous
//
#include <hip/hip_runtime.h>
#include <stdint.h>

#define TOPK 100
#define GCAP 2048
#define FIL_BLOCKS 1024
#define SLIST_CAP 2048

typedef __attribute__((ext_vector_type(8))) short bf16x8;
typedef __attribute__((ext_vector_type(4))) float f32x4;

__device__ __forceinline__ unsigned int fsort(float f) {
  unsigned int u = __float_as_uint(f);
  return (u & 0x80000000u) ? ~u : (u | 0x80000000u);
}
__device__ __forceinline__ float funsort(unsigned int k) {
  unsigned int u = (k & 0x80000000u) ? (k ^ 0x80000000u) : ~k;
  return __uint_as_float(u);
}
__device__ __forceinline__ unsigned short f2bf(float f) {
  unsigned int u = __float_as_uint(f);
  unsigned int r = (u + 0x7fffu + ((u >> 16) & 1u)) >> 16;  // RNE
  return (unsigned short)r;
}
__device__ __forceinline__ bf16x8 pack_bf(const float4& a, const float4& b) {
  bf16x8 r;
  r[0] = (short)f2bf(a.x); r[1] = (short)f2bf(a.y);
  r[2] = (short)f2bf(a.z); r[3] = (short)f2bf(a.w);
  r[4] = (short)f2bf(b.x); r[5] = (short)f2bf(b.y);
  r[6] = (short)f2bf(b.z); r[7] = (short)f2bf(b.w);
  return r;
}

// cnt is padded: user u's counter lives at cnt[u*16] (64 B apart).

// ------- Kernel 0: bf16 user panel ---------------------------------------
__global__ void k_prep(const float* __restrict__ user,
                       unsigned short* __restrict__ ubf, int n) {
  const int i = blockIdx.x * blockDim.x + threadIdx.x;
  if (i < n) ubf[i] = f2bf(user[i]);
}

// ------- Kernel 1a: MFMA sample scores (first M rows, ALL users) ----------
__global__ __launch_bounds__(256, 2) void k_sscore(
    const float* __restrict__ corpus,
    const unsigned short* __restrict__ ubf,
    float* __restrict__ sc,
    int M) {
  const int t = threadIdx.x;
  const int lane = t & 63;
  const int wave = t >> 6;
  const int l15 = lane & 15;
  const int l4  = lane >> 4;
  const int ubase = (wave & 1) * 128;

  bf16x8 bf[8][2];
#pragma unroll
  for (int ut = 0; ut < 8; ++ut) {
    const int uu = ubase + ut * 16 + l15;
#pragma unroll
    for (int kh = 0; kh < 2; ++kh)
      bf[ut][kh] = *(const bf16x8*)(ubf + uu * 64 + kh * 32 + l4 * 8);
  }

  const int ntiles_s = M >> 4;
  const int stride = gridDim.x * 2;
  for (int tile = blockIdx.x * 2 + (wave >> 1); tile < ntiles_s; tile += stride) {
    const int rb = tile << 4;
    const float4* rp = (const float4*)(corpus + (long long)(rb + l15) * 64);
    float4 a0 = rp[l4 * 2 + 0];
    float4 a1 = rp[l4 * 2 + 1];
    float4 a2 = rp[8 + l4 * 2 + 0];
    float4 a3 = rp[8 + l4 * 2 + 1];
    bf16x8 af0 = pack_bf(a0, a1);
    bf16x8 af1 = pack_bf(a2, a3);

#pragma unroll
    for (int ut = 0; ut < 8; ++ut) {
      f32x4 acc = (f32x4){0.f, 0.f, 0.f, 0.f};
      acc = __builtin_amdgcn_mfma_f32_16x16x32_bf16(af0, bf[ut][0], acc, 0, 0, 0);
      acc = __builtin_amdgcn_mfma_f32_16x16x32_bf16(af1, bf[ut][1], acc, 0, 0, 0);
      const int uu = ubase + ut * 16 + l15;
      *(float4*)(sc + (size_t)uu * M + rb + l4 * 4) =
          (float4){acc[0], acc[1], acc[2], acc[3]};
    }
  }
}

// ------- Kernel 1b: per-user threshold from sample scores + cnt zero ------
__global__ void k_thresh(const float* __restrict__ sc,
                         float* __restrict__ thr,
                         unsigned int* __restrict__ cnt,
                         int M, int rank) {
  __shared__ float s_scores[16384];
  __shared__ unsigned int s_hist[256];
  __shared__ float s_wred[8];
  __shared__ float s_bmax, s_bmin;

  const int u = blockIdx.x;
  const int t = threadIdx.x;
  if (t == 0) cnt[u * 16] = 0u;

  float lmax = -3.0e38f, lmin = 3.0e38f;
  for (int i = t; i < M; i += 256) {
    float v = sc[(size_t)u * M + i];     // coalesced
    s_scores[i] = v;
    lmax = fmaxf(lmax, v);
    lmin = fminf(lmin, v);
  }
#pragma unroll
  for (int o = 32; o > 0; o >>= 1) {
    lmax = fmaxf(lmax, __shfl_down(lmax, o));
    lmin = fminf(lmin, __shfl_down(lmin, o));
  }
  if ((t & 63) == 0) { s_wred[t >> 6] = lmax; s_wred[4 + (t >> 6)] = lmin; }
  s_hist[t] = 0u;
  __syncthreads();
  if (t == 0) {
    float bm = s_wred[0], bn = s_wred[4];
    for (int w = 1; w < 4; ++w) { bm = fmaxf(bm, s_wred[w]); bn = fminf(bn, s_wred[4 + w]); }
    s_bmax = bm; s_bmin = bn;
  }
  __syncthreads();
  const float bmax = s_bmax, bmin = s_bmin;
  const float width = (bmax - bmin) / 256.0f;
  const float inv = (width > 0.f) ? 1.0f / width : 0.f;
  for (int i = t; i < M; i += 256) {
    int b = (int)((s_scores[i] - bmin) * inv);
    b = min(max(b, 0), 255);
    atomicAdd(&s_hist[b], 1u);
  }
  __syncthreads();
  if (t == 0) {
    unsigned int cum = 0;
    int b = 255;
    for (; b >= 0; --b) { cum += s_hist[b]; if (cum >= (unsigned int)rank) break; }
    if (b < 0) b = 0;
    thr[u] = bmin + width * (float)b;    // lower edge: conservative
  }
}

// ------- Kernel 2: MFMA bf16 filter — 8 ut/wave, wave-pair tile sharing ----
// R11 single-variable change: __launch_bounds__(256,4) -> 4 blocks/CU
// (16 waves/CU, 4/SIMD), grid 1024 = exactly one resident batch.
__global__ __launch_bounds__(256, 4) void k_filter(
    const float* __restrict__ corpus,
    const unsigned short* __restrict__ ubf,
    const float* __restrict__ thr,
    unsigned int* __restrict__ cnt,
    unsigned long long* __restrict__ cand,
    int N, int CAP, int ntiles, float margin) {
  __shared__ unsigned int slist[SLIST_CAP];
  __shared__ unsigned int scnt;

  const int t = threadIdx.x;
  const int lane = t & 63;
  const int wave = t >> 6;
  const int l15 = lane & 15;
  const int l4  = lane >> 4;
  const int ubase = (wave & 1) * 128;

  if (t == 0) scnt = 0u;
  __syncthreads();

  bf16x8 bf[8][2];
  float thv[8];
#pragma unroll
  for (int ut = 0; ut < 8; ++ut) {
    const int uu = ubase + ut * 16 + l15;
#pragma unroll
    for (int kh = 0; kh < 2; ++kh)
      bf[ut][kh] = *(const bf16x8*)(ubf + uu * 64 + kh * 32 + l4 * 8);
    thv[ut] = thr[uu] - margin;
  }

  const int stride = FIL_BLOCKS * 2;
  int tile = blockIdx.x * 2 + (wave >> 1);

  if (tile < ntiles) {
    // prologue: load + convert first tile
    const float4* rp = (const float4*)(corpus + (long long)min(tile * 16 + l15, N - 1) * 64);
    bf16x8 af0, af1;
    {
      float4 a0 = rp[l4 * 2 + 0];
      float4 a1 = rp[l4 * 2 + 1];
      float4 a2 = rp[8 + l4 * 2 + 0];
      float4 a3 = rp[8 + l4 * 2 + 1];
      af0 = pack_bf(a0, a1);
      af1 = pack_bf(a2, a3);
    }

    for (;;) {
      const int next = tile + stride;
      const bool have_next = (next < ntiles);
      float4 n0, n1, n2, n3;
      if (have_next) {                     // prefetch raw f32 (hidden by compute)
        const float4* rp2 = (const float4*)(corpus + (long long)min(next * 16 + l15, N - 1) * 64);
        n0 = rp2[l4 * 2 + 0];
        n1 = rp2[l4 * 2 + 1];
        n2 = rp2[8 + l4 * 2 + 0];
        n3 = rp2[8 + l4 * 2 + 1];
      }

      const int rb = tile << 4;
#pragma unroll
      for (int ut = 0; ut < 8; ++ut) {
        f32x4 acc = (f32x4){0.f, 0.f, 0.f, 0.f};
        acc = __builtin_amdgcn_mfma_f32_16x16x32_bf16(af0, bf[ut][0], acc, 0, 0, 0);
        acc = __builtin_amdgcn_mfma_f32_16x16x32_bf16(af1, bf[ut][1], acc, 0, 0, 0);
        bool hit = (acc[0] >= thv[ut]) | (acc[1] >= thv[ut]) |
                   (acc[2] >= thv[ut]) | (acc[3] >= thv[ut]);
        if (__ballot(hit)) {
          const unsigned int uu = (unsigned int)(ubase + ut * 16 + l15);
#pragma unroll
          for (int r = 0; r < 4; ++r) {
            const int row = rb + l4 * 4 + r;
            if (acc[r] >= thv[ut] && row < N) {
              unsigned int pos = atomicAdd(&scnt, 1u);
              if (pos < SLIST_CAP) {
                slist[pos] = (uu << 20) | (unsigned int)row;
              } else {  // fallback: direct global append
                unsigned int gp = atomicAdd(&cnt[uu * 16], 1u);
                if (gp < (unsigned int)CAP)
                  cand[(size_t)uu * (size_t)CAP + gp] = (unsigned long long)(unsigned int)row;
              }
            }
          }
        }
      }

      if (!have_next) break;
      af0 = pack_bf(n0, n1);               // convert once; raw regs die here
      af1 = pack_bf(n2, n3);
      tile = next;
    }
  }

  __syncthreads();
  // flush: thread t owns user t; two broadcast scans
  const int n = min((int)scnt, SLIST_CAP);
  const unsigned int me = (unsigned int)t;
  unsigned int c = 0;
  for (int i = 0; i < n; ++i)
    if ((slist[i] >> 20) == me) ++c;
  unsigned int base = 0;
  if (c) base = atomicAdd(&cnt[me * 16], c);
  if (c) {
    unsigned int k = 0;
    for (int i = 0; i < n; ++i) {
      unsigned int v = slist[i];
      if ((v >> 20) == me) {
        unsigned int p = base + k;
        if (p < (unsigned int)CAP)
          cand[(size_t)me * (size_t)CAP + p] = (unsigned long long)(v & 0xFFFFFu);
        ++k;
      }
    }
  }
}

// ------- Kernel 3: exact fp32 rescore of survivors ------------------------
__global__ void k_rescore(const float* __restrict__ user,
                          const float* __restrict__ corpus,
                          const unsigned int* __restrict__ cnt,
                          unsigned long long* __restrict__ cand,
                          int CAP) {
  __shared__ float su[64];
  const int u = blockIdx.x >> 2;
  const int q = blockIdx.x & 3;
  const int t = threadIdx.x;
  if (t < 64) su[t] = user[u * 64 + t];
  __syncthreads();
  float uv[64];
#pragma unroll
  for (int i = 0; i < 64; ++i) uv[i] = su[i];
  const int n = min((int)cnt[u * 16], CAP);
  for (int i = q * 256 + t; i < n; i += 1024) {
    const unsigned int row = (unsigned int)cand[(size_t)u * (size_t)CAP + i];
    const float4* rp = (const float4*)(corpus + (size_t)row * 64);
    float acc = 0.f;
#pragma unroll
    for (int k = 0; k < 16; ++k) {
      float4 c = rp[k];
      acc = fmaf(uv[4*k+0], c.x, acc);
      acc = fmaf(uv[4*k+1], c.y, acc);
      acc = fmaf(uv[4*k+2], c.z, acc);
      acc = fmaf(uv[4*k+3], c.w, acc);
    }
    cand[(size_t)u * (size_t)CAP + i] = ((unsigned long long)fsort(acc) << 32)
                                      | (unsigned long long)(~row);
  }
}

// ------- Kernel 4: exact top-100 per user ---------------------------------
__global__ void k_select(const unsigned long long* __restrict__ cand,
                         const unsigned int* __restrict__ cnt,
                         float* __restrict__ out,
                         int B, int CAP) {
  __shared__ unsigned long long keys[GCAP];
  __shared__ unsigned int hist[1024];
  __shared__ unsigned int s_kmax, s_kmin, s_gcnt;
  __shared__ int s_bstar;

  const int u = blockIdx.x;
  const int t = threadIdx.x;
  const int n = min((int)cnt[u * 16], CAP);
  const unsigned long long* cu = cand + (size_t)u * (size_t)CAP;

  if (t == 0) { s_kmax = 0u; s_kmin = 0xFFFFFFFFu; s_gcnt = 0u; }
  for (int i = t; i < 1024; i += 256) hist[i] = 0u;
  __syncthreads();

  unsigned int lmax = 0u, lmin = 0xFFFFFFFFu;
  for (int i = t; i < n; i += 256) {
    unsigned int k = (unsigned int)(cu[i] >> 32);
    lmax = max(lmax, k); lmin = min(lmin, k);
  }
#pragma unroll
  for (int o = 32; o > 0; o >>= 1) {
    lmax = max(lmax, __shfl_down(lmax, o));
    lmin = min(lmin, __shfl_down(lmin, o));
  }
  if ((t & 63) == 0) { atomicMax(&s_kmax, lmax); atomicMin(&s_kmin, lmin); }
  __syncthreads();
  const unsigned int kmax = s_kmax, kmin = s_kmin;
  const unsigned long long range = (unsigned long long)(kmax - kmin) + 1ull;

  for (int i = t; i < n; i += 256) {
    unsigned int k = (unsigned int)(cu[i] >> 32);
    unsigned int b = (unsigned int)((((unsigned long long)(k - kmin)) << 10) / range);
    atomicAdd(&hist[min(b, 1023u)], 1u);
  }
  __syncthreads();
  if (t == 0) {
    unsigned int cum = 0;
    int b = 1023;
    for (; b >= 0; --b) { cum += hist[b]; if (cum >= TOPK) break; }
    s_bstar = (b < 0) ? 0 : b;
  }
  __syncthreads();
  const unsigned int bstar = (unsigned int)s_bstar;

  for (int i = t; i < n; i += 256) {
    unsigned long long key = cu[i];
    unsigned int k = (unsigned int)(key >> 32);
    unsigned int b = min((unsigned int)((((unsigned long long)(k - kmin)) << 10) / range), 1023u);
    if (b >= bstar) {
      unsigned int pos = atomicAdd(&s_gcnt, 1u);
      if (pos < GCAP) keys[pos] = key;
    }
  }
  __syncthreads();
  const int g = min((int)s_gcnt, GCAP);
  int S = 128;
  while (S < g) S <<= 1;
  for (int i = g + t; i < S; i += 256) keys[i] = 0ull;
  __syncthreads();

  for (int k = 2; k <= S; k <<= 1) {
    for (int j = k >> 1; j > 0; j >>= 1) {
      for (int i = t; i < S; i += 256) {
        int ixj = i ^ j;
        if (ixj > i) {
          unsigned long long a = keys[i], b2 = keys[ixj];
          bool descSeg = ((i & k) == 0);
          bool sw = descSeg ? (a < b2) : (a > b2);
          if (sw) { keys[i] = b2; keys[ixj] = a; }
        }
      }
      __syncthreads();
    }
  }

  if (t < TOPK) {
    unsigned long long key = keys[t];
    unsigned int kk = (unsigned int)(key >> 32);
    unsigned int idx = ~(unsigned int)(key & 0xFFFFFFFFull);
    out[u * TOPK + t] = funsort(kk);
    out[(size_t)B * TOPK + u * TOPK + t] = (float)idx;
  }
}

extern "C" void kernel_launch(void* const* d_in, const int* in_sizes, int n_in,
                              void* d_out, int out_size, void* d_ws, size_t ws_size,
                              hipStream_t stream) {
  const float* user = (const float*)d_in[0];
  const float* corpus = (const float*)d_in[1];
  float* out = (float*)d_out;
  const int B = in_sizes[0] / 64;           // 256
  const int N = in_sizes[1] / 64;           // 1,000,000

  // ws: cnt_pad[B*16] u32 @0 (16 KB) | thr[B] f32 @16384 | ubf[B*64] u16 @17408
  //     | sc f32 [B*M] @50176 | cand u64 after sc
  unsigned int* cnt = (unsigned int*)d_ws;
  float* thr = (float*)((char*)d_ws + 16384);
  unsigned short* ubf = (unsigned short*)((char*)d_ws + 17408);
  const size_t sc_off = 50176;

  int CAP = 4096;                    // survivors ~1100 +/- 280
  long long M = 16384;
  long long need = (long long)sc_off + M * B * 4 + (long long)B * CAP * 8;
  if ((long long)ws_size < need) {   // degrade M first (1 KB per row), then CAP
    long long spare = (long long)ws_size - sc_off - (long long)B * CAP * 8;
    M = (spare / (B * 4)) & ~1023LL;
    if (M < 4096) {
      M = 4096;
      long long spare2 = (long long)ws_size - sc_off - M * B * 4;
      CAP = (int)(spare2 / ((long long)B * 8));
      if (CAP < 256) CAP = 256;
    }
  }
  if (M > (long long)N) M = (long long)(N & ~1023);
  float* sc = (float*)((char*)d_ws + sc_off);
  unsigned long long* cand = (unsigned long long*)((char*)d_ws + sc_off + (size_t)(M * B * 4));

  const int RANK = (int)(M >> 10);          // 16 @ M=16384
  const float MARGIN = 0.25f;
  const int ntiles = (N + 15) >> 4;

  k_prep<<<(B * 64 + 255) / 256, 256, 0, stream>>>(user, ubf, B * 64);
  k_sscore<<<256, 256, 0, stream>>>(corpus, ubf, sc, (int)M);
  k_thresh<<<B, 256, 0, stream>>>(sc, thr, cnt, (int)M, RANK);
  k_filter<<<FIL_BLOCKS, 256, 0, stream>>>(corpus, ubf, thr, cnt, cand, N, CAP, ntiles, MARGIN);
  k_rescore<<<B * 4, 256, 0, stream>>>(user, corpus, cnt, cand, CAP);
  k_select<<<B, 256, 0, stream>>>(cand, cnt, out, B, CAP);
}